// Round 5
// baseline (788.268 us; speedup 1.0000x reference)
//
#include <hip/hip_runtime.h>

typedef unsigned short u16;
typedef unsigned int u32;

#define Bb 2
#define Lc 2048
#define Dc 2048
#define Hc 16
#define DhC 128

typedef __bf16 bf16x8 __attribute__((ext_vector_type(8)));
typedef float f32x4 __attribute__((ext_vector_type(4)));

__device__ __forceinline__ u16 f2b(float f) {
  u32 u = __float_as_uint(f);
  u32 r = (u + 0x7fffu + ((u >> 16) & 1u)) >> 16;
  return (u16)r;
}
__device__ __forceinline__ float b2f(u16 u) {
  return __uint_as_float(((u32)u) << 16);
}

// async global->LDS DMA, 16B per lane (m97: the 517->874 TF step)
__device__ __forceinline__ void gll16(const void* g, void* l) {
  __builtin_amdgcn_global_load_lds(
      (const __attribute__((address_space(1))) u32*)g,
      (__attribute__((address_space(3))) u32*)l, 16, 0, 0);
}

// ---------------------------------------------------------------------------
// Dtype sniffer (kept from r4-pass): fp32 inputs read as bf16 -> wild values.
// ---------------------------------------------------------------------------
__global__ __launch_bounds__(256) void sniff_dtype(const u16* __restrict__ x,
                                                   int* __restrict__ flag) {
  __shared__ int bad;
  if (threadIdx.x == 0) bad = 0;
  __syncthreads();
  int local = 0;
  for (int i = threadIdx.x; i < 65536; i += 256) {
    float v = fabsf(b2f(x[i]));
    if (!(v < 1000.f)) local = 1;
  }
  if (local) atomicOr(&bad, 1);
  __syncthreads();
  if (threadIdx.x == 0) *flag = bad;
}

__global__ __launch_bounds__(256) void conv_x(const void* __restrict__ in,
                                              u16* __restrict__ out,
                                              const int* __restrict__ flag) {
  const int f32 = *flag;
  const int i0 = (blockIdx.x * 256 + threadIdx.x) * 4;
  if (f32) {
    const float* p = (const float*)in;
#pragma unroll
    for (int j = 0; j < 4; j++) out[i0 + j] = f2b(p[i0 + j]);
  } else {
    const u16* p = (const u16*)in;
#pragma unroll
    for (int j = 0; j < 4; j++) out[i0 + j] = p[i0 + j];
  }
}

// ---------------------------------------------------------------------------
// 2048x2048 transpose with dtype conversion (weights -> bf16 W^T).
// ---------------------------------------------------------------------------
__global__ __launch_bounds__(256) void transpose2d_conv(const void* __restrict__ in,
                                                        u16* __restrict__ out,
                                                        const int* __restrict__ flag) {
  __shared__ __align__(16) u16 tile[64][65];
  const int f32 = *flag;
  const int r0 = blockIdx.y * 64, c0 = blockIdx.x * 64;
  const int tc = threadIdx.x & 63, tr4 = threadIdx.x >> 6;
#pragma unroll
  for (int p = 0; p < 16; p++) {
    int r = tr4 + p * 4;
    size_t idx = (size_t)(r0 + r) * 2048 + c0 + tc;
    tile[r][tc] = f32 ? f2b(((const float*)in)[idx]) : ((const u16*)in)[idx];
  }
  __syncthreads();
#pragma unroll
  for (int p = 0; p < 16; p++) {
    int rr = tr4 + p * 4;
    out[(size_t)(c0 + rr) * 2048 + r0 + tc] = tile[tc][rr];
  }
}

// ---------------------------------------------------------------------------
// GEMM core: C[4096,2048] = A @ Bt^T, m97 structure: 128x128 tile, BK=64,
// global_load_lds width-16 staging into UNPADDED LDS (DMA dest must be
// base + lane*16 contiguous -- padding is illegal here, per guide m104/m108).
// Templated on output writer (bf16 or fp32).
// ---------------------------------------------------------------------------
template <typename OutT>
__device__ __forceinline__ void gemm_bt_core(const u16* __restrict__ A,
                                             const u16* __restrict__ Bt,
                                             OutT* __restrict__ C) {
  constexpr int K = 2048, N = 2048;
  __shared__ __align__(16) u16 As[128 * 64];  // row-major 128x64, rows 128B
  __shared__ __align__(16) u16 Bs[128 * 64];
  const int tid = threadIdx.x;
  const int lane = tid & 63, wid = tid >> 6;
  const int wm = (wid >> 1) * 64, wn = (wid & 1) * 64;
  const int m0 = blockIdx.x * 128, n0 = blockIdx.y * 128;
  const int quad = lane >> 4, l15 = lane & 15;

  const f32x4 fz = {0.f, 0.f, 0.f, 0.f};
  f32x4 acc[4][4];
#pragma unroll
  for (int i = 0; i < 4; i++)
#pragma unroll
    for (int j = 0; j < 4; j++) acc[i][j] = fz;

  for (int k0 = 0; k0 < K; k0 += 64) {
    // stage A,B tiles: chunk c = p*256+tid -> row c>>3, col (c&7)*8
    // LDS dest: wave-uniform base (p*256 + wid*64)*8 elems; HW adds lane*16B
#pragma unroll
    for (int p = 0; p < 4; p++) {
      const int c = p * 256 + tid;
      const int r = c >> 3, cg = (c & 7) * 8;
      u16* lbase = As + (p * 256 + wid * 64) * 8;
      gll16(A + (size_t)(m0 + r) * K + k0 + cg, lbase);
    }
#pragma unroll
    for (int p = 0; p < 4; p++) {
      const int c = p * 256 + tid;
      const int r = c >> 3, cg = (c & 7) * 8;
      u16* lbase = Bs + (p * 256 + wid * 64) * 8;
      gll16(Bt + (size_t)(n0 + r) * K + k0 + cg, lbase);
    }
    __syncthreads();
#pragma unroll
    for (int ks = 0; ks < 2; ks++) {
      bf16x8 af[4], bfr[4];
#pragma unroll
      for (int t = 0; t < 4; t++) {
        af[t]  = *(const bf16x8*)(&As[(wm + t * 16 + l15) * 64 + ks * 32 + quad * 8]);
        bfr[t] = *(const bf16x8*)(&Bs[(wn + t * 16 + l15) * 64 + ks * 32 + quad * 8]);
      }
#pragma unroll
      for (int mt = 0; mt < 4; mt++)
#pragma unroll
        for (int nt = 0; nt < 4; nt++)
          acc[mt][nt] = __builtin_amdgcn_mfma_f32_16x16x32_bf16(af[mt], bfr[nt], acc[mt][nt], 0, 0, 0);
    }
    __syncthreads();
  }
#pragma unroll
  for (int mt = 0; mt < 4; mt++)
#pragma unroll
    for (int nt = 0; nt < 4; nt++) {
      int col = n0 + wn + nt * 16 + l15;
#pragma unroll
      for (int r = 0; r < 4; r++) {
        int row = m0 + wm + mt * 16 + quad * 4 + r;
        float v = acc[mt][nt][r];
        if constexpr (sizeof(OutT) == 2)
          C[(size_t)row * N + col] = f2b(v);
        else
          C[(size_t)row * N + col] = v;
      }
    }
}

__global__ __launch_bounds__(256) void gemm_bt(const u16* __restrict__ A,
                                               const u16* __restrict__ Bt,
                                               u16* __restrict__ C) {
  gemm_bt_core<u16>(A, Bt, C);
}
__global__ __launch_bounds__(256) void gemm_bt_f32(const u16* __restrict__ A,
                                                   const u16* __restrict__ Bt,
                                                   float* __restrict__ C) {
  gemm_bt_core<float>(A, Bt, C);
}

// ---------------------------------------------------------------------------
// V (B,L,H,Dh) -> Vt (B,H,Dh,L)
// ---------------------------------------------------------------------------
__global__ __launch_bounds__(256) void transpose_v_k(const u16* __restrict__ V,
                                                     u16* __restrict__ Vt) {
  __shared__ __align__(16) u16 tile[64][65];
  const int z = blockIdx.z;
  const int b = z >> 4, h = z & 15;
  const int l0 = blockIdx.y * 64, d0 = blockIdx.x * 64;
  const int tc = threadIdx.x & 63, tr4 = threadIdx.x >> 6;
#pragma unroll
  for (int p = 0; p < 16; p++) {
    int l = tr4 + p * 4;
    tile[l][tc] = V[(size_t)((b * Lc + l0 + l) * Hc + h) * DhC + d0 + tc];
  }
  __syncthreads();
#pragma unroll
  for (int p = 0; p < 16; p++) {
    int dd = tr4 + p * 4;
    Vt[((size_t)z * DhC + d0 + dd) * Lc + l0 + tc] = tile[tc][dd];
  }
}

// ---------------------------------------------------------------------------
// RoPE in place on Q and K; Q additionally scaled by 1/sqrt(Dh).
// ---------------------------------------------------------------------------
__global__ __launch_bounds__(256) void rope_qk(u16* __restrict__ Q, u16* __restrict__ K) {
  const int idx = blockIdx.x * 256 + threadIdx.x;
  const int j = idx & 63;
  const int l = (idx >> 10) & 2047;
  const float inv = expf(-0.2050369278f * (float)j);  // theta^(-j/64)
  const float ang = (float)l * inv;
  float s, c;
  sincosf(ang, &s, &c);
  const size_t off = (size_t)idx * 2;
  const float q0 = b2f(Q[off]), q1 = b2f(Q[off + 1]);
  const float k0 = b2f(K[off]), k1 = b2f(K[off + 1]);
  const float sc = 0.08838834764f;  // 1/sqrt(128)
  Q[off]     = f2b((q0 * c - q1 * s) * sc);
  Q[off + 1] = f2b((q1 * c + q0 * s) * sc);
  K[off]     = f2b(k0 * c - k1 * s);
  K[off + 1] = f2b(k1 * c + k0 * s);
}

// ---------------------------------------------------------------------------
// Flash attention (causal). r5 changes vs r4 (206us, MfmaUtil 6.8%, Occ 12%):
//  - heavy-first dispatch: qt = 31 - blockIdx.x (long blocks start at t=0)
//  - register prefetch: next K/V tile loaded into VGPRs BEFORE compute of the
//    current tile, so the ~900cy HBM latency hides behind QK/softmax/PV.
// LDS layout/padding unchanged (45KB -> 3 blocks/CU).
// ---------------------------------------------------------------------------
#define NEGBIG (-3.0e30f)
__global__ __launch_bounds__(256) void flash_attn(const u16* __restrict__ Q,
                                                  const u16* __restrict__ Kg,
                                                  const u16* __restrict__ Vt,
                                                  u16* __restrict__ O) {
  __shared__ __align__(16) u16 Ks[64][136];
  __shared__ __align__(16) u16 Vs[128][72];
  __shared__ __align__(16) u16 Ps[4][16][72];
  const int tid = threadIdx.x;
  const int lane = tid & 63, w = tid >> 6;
  const int quad = lane >> 4, l15 = lane & 15;
  const int qt = (int)gridDim.x - 1 - (int)blockIdx.x;  // heavy first
  const int bh = blockIdx.y;
  const int b = bh >> 4, h = bh & 15;
  const int q0 = qt * 64;
  const int qrow = q0 + w * 16 + l15;

  bf16x8 aq[4];
  const u16* qptr = Q + ((size_t)(b * Lc + qrow) * Hc + h) * DhC + quad * 8;
#pragma unroll
  for (int ks = 0; ks < 4; ks++) aq[ks] = *(const bf16x8*)(qptr + ks * 32);

  const f32x4 fz = {0.f, 0.f, 0.f, 0.f};
  f32x4 o[8];
#pragma unroll
  for (int f = 0; f < 8; f++) o[f] = fz;
  float mrow[4], lrow[4];
#pragma unroll
  for (int r = 0; r < 4; r++) { mrow[r] = NEGBIG; lrow[r] = 0.f; }

  // staging indices
  const int kr = tid >> 4, kc = (tid & 15) * 8;   // K: 16 rows/pass x 4
  const int vd = tid >> 3, vc = (tid & 7) * 8;    // V: 32 d-rows/pass x 4

  uint4 kreg[4], vreg[4];
  // prologue: load tile 0
#pragma unroll
  for (int p = 0; p < 4; p++)
    kreg[p] = *(const uint4*)(Kg + ((size_t)(b * Lc + kr + p * 16) * Hc + h) * DhC + kc);
#pragma unroll
  for (int p = 0; p < 4; p++)
    vreg[p] = *(const uint4*)(Vt + ((size_t)bh * DhC + vd + p * 32) * Lc + vc);

  for (int kvt = 0; kvt <= qt; kvt++) {
    // commit prefetched tile to LDS
#pragma unroll
    for (int p = 0; p < 4; p++) *(uint4*)(&Ks[kr + p * 16][kc]) = kreg[p];
#pragma unroll
    for (int p = 0; p < 4; p++) *(uint4*)(&Vs[vd + p * 32][vc]) = vreg[p];
    __syncthreads();

    // issue next tile's loads NOW -- they complete during compute below
    if (kvt < qt) {
      const int nv0 = (kvt + 1) * 64;
#pragma unroll
      for (int p = 0; p < 4; p++)
        kreg[p] = *(const uint4*)(Kg + ((size_t)(b * Lc + nv0 + kr + p * 16) * Hc + h) * DhC + kc);
#pragma unroll
      for (int p = 0; p < 4; p++)
        vreg[p] = *(const uint4*)(Vt + ((size_t)bh * DhC + vd + p * 32) * Lc + nv0 + vc);
    }

    // S = Q @ K^T
    f32x4 s[4];
#pragma unroll
    for (int ct = 0; ct < 4; ct++) s[ct] = fz;
#pragma unroll
    for (int ks = 0; ks < 4; ks++) {
#pragma unroll
      for (int ct = 0; ct < 4; ct++) {
        bf16x8 bk = *(const bf16x8*)(&Ks[ct * 16 + l15][ks * 32 + quad * 8]);
        s[ct] = __builtin_amdgcn_mfma_f32_16x16x32_bf16(aq[ks], bk, s[ct], 0, 0, 0);
      }
    }

    if (kvt == qt) {
      const int kv0 = kvt * 64;
#pragma unroll
      for (int ct = 0; ct < 4; ct++) {
        int kvc = kv0 + ct * 16 + l15;
#pragma unroll
        for (int r = 0; r < 4; r++) {
          int qr = q0 + w * 16 + quad * 4 + r;
          if (kvc > qr) s[ct][r] = NEGBIG;
        }
      }
    }

    // online softmax (rows live across 16 lanes of a quad)
    float mnew[4], alpha[4];
#pragma unroll
    for (int r = 0; r < 4; r++) {
      float mx = fmaxf(fmaxf(s[0][r], s[1][r]), fmaxf(s[2][r], s[3][r]));
#pragma unroll
      for (int off = 1; off < 16; off <<= 1) mx = fmaxf(mx, __shfl_xor(mx, off, 64));
      mnew[r] = fmaxf(mrow[r], mx);
      alpha[r] = __expf(mrow[r] - mnew[r]);
      mrow[r] = mnew[r];
    }
    float psum[4] = {0.f, 0.f, 0.f, 0.f};
#pragma unroll
    for (int ct = 0; ct < 4; ct++) {
#pragma unroll
      for (int r = 0; r < 4; r++) {
        float p = __expf(s[ct][r] - mnew[r]);
        s[ct][r] = p;
        psum[r] += p;
      }
    }
#pragma unroll
    for (int r = 0; r < 4; r++) {
#pragma unroll
      for (int off = 1; off < 16; off <<= 1) psum[r] += __shfl_xor(psum[r], off, 64);
      lrow[r] = lrow[r] * alpha[r] + psum[r];
    }
#pragma unroll
    for (int f = 0; f < 8; f++)
#pragma unroll
      for (int r = 0; r < 4; r++) o[f][r] *= alpha[r];

    // P: C-layout -> LDS -> A-layout
#pragma unroll
    for (int ct = 0; ct < 4; ct++)
#pragma unroll
      for (int r = 0; r < 4; r++)
        Ps[w][quad * 4 + r][ct * 16 + l15] = f2b(s[ct][r]);
    __syncthreads();

#pragma unroll
    for (int ks = 0; ks < 2; ks++) {
      bf16x8 ap = *(const bf16x8*)(&Ps[w][l15][ks * 32 + quad * 8]);
#pragma unroll
      for (int f = 0; f < 8; f++) {
        bf16x8 bv = *(const bf16x8*)(&Vs[f * 16 + l15][ks * 32 + quad * 8]);
        o[f] = __builtin_amdgcn_mfma_f32_16x16x32_bf16(ap, bv, o[f], 0, 0, 0);
      }
    }
    __syncthreads();
  }

#pragma unroll
  for (int f = 0; f < 8; f++) {
    int d = f * 16 + l15;
#pragma unroll
    for (int r = 0; r < 4; r++) {
      int qr = q0 + w * 16 + quad * 4 + r;
      O[((size_t)(b * Lc + qr) * Hc + h) * DhC + d] = f2b(o[f][r] / lrow[r]);
    }
  }
}

// ---------------------------------------------------------------------------
// ws layout (72 MiB + 256 B peak), serial weight-slot reuse:
//   [0,256) flag | WT 8MiB | xc 16MiB | Qb 16MiB | Kb 16MiB | Vb 16MiB
//   Vtb aliases xc (dead after V-gemm); Ob aliases Vb (dead after v-transpose)
// ---------------------------------------------------------------------------
extern "C" void kernel_launch(void* const* d_in, const int* in_sizes, int n_in,
                              void* d_out, int out_size, void* d_ws, size_t ws_size,
                              hipStream_t stream) {
  const void* x  = d_in[0];
  const void* Wq = d_in[1];
  const void* Wk = d_in[2];
  const void* Wv = d_in[3];
  const void* Wo = d_in[4];
  float* out = (float*)d_out;   // reference output dtype: float32 (verified r4)

  char* w = (char*)d_ws;
  const size_t WSZ = (size_t)2048 * 2048;
  const size_t XSZ = (size_t)Bb * Lc * Dc;
  int* flag = (int*)w;
  u16* WT  = (u16*)(w + 256);
  u16* xc  = WT + WSZ;
  u16* Qb  = xc + XSZ;
  u16* Kb  = Qb + XSZ;
  u16* Vb  = Kb + XSZ;
  u16* Vtb = xc;
  u16* Ob  = Vb;

  sniff_dtype<<<1, 256, 0, stream>>>((const u16*)x, flag);
  conv_x<<<(int)(XSZ / 1024), 256, 0, stream>>>(x, xc, flag);

  dim3 tgrid(32, 32);
  dim3 ggrid(32, 16);

  transpose2d_conv<<<tgrid, 256, 0, stream>>>(Wq, WT, flag);
  gemm_bt<<<ggrid, 256, 0, stream>>>(xc, WT, Qb);
  transpose2d_conv<<<tgrid, 256, 0, stream>>>(Wk, WT, flag);
  gemm_bt<<<ggrid, 256, 0, stream>>>(xc, WT, Kb);
  transpose2d_conv<<<tgrid, 256, 0, stream>>>(Wv, WT, flag);
  gemm_bt<<<ggrid, 256, 0, stream>>>(xc, WT, Vb);

  rope_qk<<<(Bb * Lc * Hc * 64) / 256, 256, 0, stream>>>(Qb, Kb);

  dim3 vgrid(2, 32, 32);
  transpose_v_k<<<vgrid, 256, 0, stream>>>(Vb, Vtb);

  dim3 fgrid(32, 32);
  flash_attn<<<fgrid, 256, 0, stream>>>(Qb, Kb, Vtb, Ob);

  transpose2d_conv<<<tgrid, 256, 0, stream>>>(Wo, WT, flag);
  gemm_bt_f32<<<ggrid, 256, 0, stream>>>(Ob, WT, out);
}

// Round 6
// 586.834 us; speedup vs baseline: 1.3433x; 1.3433x over previous
//
#include <hip/hip_runtime.h>

typedef unsigned short u16;
typedef unsigned int u32;

#define Bb 2
#define Lc 2048
#define Dc 2048
#define Hc 16
#define DhC 128

typedef __bf16 bf16x8 __attribute__((ext_vector_type(8)));
typedef float f32x4 __attribute__((ext_vector_type(4)));

__device__ __forceinline__ u16 f2b(float f) {
  u32 u = __float_as_uint(f);
  u32 r = (u + 0x7fffu + ((u >> 16) & 1u)) >> 16;
  return (u16)r;
}
__device__ __forceinline__ float b2f(u16 u) {
  return __uint_as_float(((u32)u) << 16);
}

// async global->LDS DMA, 16B/lane; LDS dest = wave-uniform base + lane*16
__device__ __forceinline__ void gll16(const void* g, void* l) {
  __builtin_amdgcn_global_load_lds(
      (const __attribute__((address_space(1))) u32*)g,
      (__attribute__((address_space(3))) u32*)l, 16, 0, 0);
}

// ---------------------------------------------------------------------------
// Dtype sniffer + x canonicalize (kept; inputs verified bf16-compatible r4).
// ---------------------------------------------------------------------------
__global__ __launch_bounds__(256) void sniff_dtype(const u16* __restrict__ x,
                                                   int* __restrict__ flag) {
  __shared__ int bad;
  if (threadIdx.x == 0) bad = 0;
  __syncthreads();
  int local = 0;
  for (int i = threadIdx.x; i < 65536; i += 256) {
    float v = fabsf(b2f(x[i]));
    if (!(v < 1000.f)) local = 1;
  }
  if (local) atomicOr(&bad, 1);
  __syncthreads();
  if (threadIdx.x == 0) *flag = bad;
}

__global__ __launch_bounds__(256) void conv_x(const void* __restrict__ in,
                                              u16* __restrict__ out,
                                              const int* __restrict__ flag) {
  const int f32 = *flag;
  const int i0 = (blockIdx.x * 256 + threadIdx.x) * 4;
  if (f32) {
    const float* p = (const float*)in;
#pragma unroll
    for (int j = 0; j < 4; j++) out[i0 + j] = f2b(p[i0 + j]);
  } else {
    const u16* p = (const u16*)in;
#pragma unroll
    for (int j = 0; j < 4; j++) out[i0 + j] = p[i0 + j];
  }
}

// ---------------------------------------------------------------------------
// 2048x2048 transpose with dtype conversion (weights -> bf16 W^T).
// ---------------------------------------------------------------------------
__global__ __launch_bounds__(256) void transpose2d_conv(const void* __restrict__ in,
                                                        u16* __restrict__ out,
                                                        const int* __restrict__ flag) {
  __shared__ __align__(16) u16 tile[64][65];
  const int f32 = *flag;
  const int r0 = blockIdx.y * 64, c0 = blockIdx.x * 64;
  const int tc = threadIdx.x & 63, tr4 = threadIdx.x >> 6;
#pragma unroll
  for (int p = 0; p < 16; p++) {
    int r = tr4 + p * 4;
    size_t idx = (size_t)(r0 + r) * 2048 + c0 + tc;
    tile[r][tc] = f32 ? f2b(((const float*)in)[idx]) : ((const u16*)in)[idx];
  }
  __syncthreads();
#pragma unroll
  for (int p = 0; p < 16; p++) {
    int rr = tr4 + p * 4;
    out[(size_t)(c0 + rr) * 2048 + r0 + tc] = tile[tc][rr];
  }
}

// ---------------------------------------------------------------------------
// GEMM: C[4096,2048] = A @ Bt^T. m97 structure + XOR-swizzled LDS:
// row r (64 elems = 8 chunks of 16B): logical chunk c stored at slot c^(r&7).
// Read banks: bijective per 8-row group -> 2 lanes/bank (free, m136).
// ---------------------------------------------------------------------------
template <typename OutT>
__device__ __forceinline__ void gemm_bt_core(const u16* __restrict__ A,
                                             const u16* __restrict__ Bt,
                                             OutT* __restrict__ C) {
  constexpr int K = 2048, N = 2048;
  __shared__ __align__(16) u16 As[128 * 64];
  __shared__ __align__(16) u16 Bs[128 * 64];
  const int tid = threadIdx.x;
  const int lane = tid & 63, wid = tid >> 6;
  const int wm = (wid >> 1) * 64, wn = (wid & 1) * 64;
  const int m0 = blockIdx.x * 128, n0 = blockIdx.y * 128;
  const int quad = lane >> 4, l15 = lane & 15;
  const int sw = l15 & 7;  // read-side swizzle key

  const f32x4 fz = {0.f, 0.f, 0.f, 0.f};
  f32x4 acc[4][4];
#pragma unroll
  for (int i = 0; i < 4; i++)
#pragma unroll
    for (int j = 0; j < 4; j++) acc[i][j] = fz;

  // staging map (per wave, per pass p): rows p*32+wid*8+(lane>>3), slot lane&7
  const int srl = (lane >> 3);
  const int ssl = lane & 7;

  for (int k0 = 0; k0 < K; k0 += 64) {
#pragma unroll
    for (int p = 0; p < 4; p++) {
      const int r = p * 32 + wid * 8 + srl;
      const int c = ssl ^ (r & 7);
      u16* lb = As + (p * 256 + wid * 64) * 8;
      gll16(A + (size_t)(m0 + r) * K + k0 + c * 8, lb);
    }
#pragma unroll
    for (int p = 0; p < 4; p++) {
      const int r = p * 32 + wid * 8 + srl;
      const int c = ssl ^ (r & 7);
      u16* lb = Bs + (p * 256 + wid * 64) * 8;
      gll16(Bt + (size_t)(n0 + r) * K + k0 + c * 8, lb);
    }
    __syncthreads();
#pragma unroll
    for (int ks = 0; ks < 2; ks++) {
      bf16x8 af[4], bfr[4];
#pragma unroll
      for (int t = 0; t < 4; t++) {
        const int cc = ((ks * 4 + quad) ^ sw) * 8;
        af[t]  = *(const bf16x8*)(&As[(wm + t * 16 + l15) * 64 + cc]);
        bfr[t] = *(const bf16x8*)(&Bs[(wn + t * 16 + l15) * 64 + cc]);
      }
#pragma unroll
      for (int mt = 0; mt < 4; mt++)
#pragma unroll
        for (int nt = 0; nt < 4; nt++)
          acc[mt][nt] = __builtin_amdgcn_mfma_f32_16x16x32_bf16(af[mt], bfr[nt], acc[mt][nt], 0, 0, 0);
    }
    __syncthreads();
  }
#pragma unroll
  for (int mt = 0; mt < 4; mt++)
#pragma unroll
    for (int nt = 0; nt < 4; nt++) {
      int col = n0 + wn + nt * 16 + l15;
#pragma unroll
      for (int r = 0; r < 4; r++) {
        int row = m0 + wm + mt * 16 + quad * 4 + r;
        float v = acc[mt][nt][r];
        if constexpr (sizeof(OutT) == 2)
          C[(size_t)row * N + col] = f2b(v);
        else
          C[(size_t)row * N + col] = v;
      }
    }
}

__global__ __launch_bounds__(256) void gemm_bt(const u16* __restrict__ A,
                                               const u16* __restrict__ Bt,
                                               u16* __restrict__ C) {
  gemm_bt_core<u16>(A, Bt, C);
}
__global__ __launch_bounds__(256) void gemm_bt_f32(const u16* __restrict__ A,
                                                   const u16* __restrict__ Bt,
                                                   float* __restrict__ C) {
  gemm_bt_core<float>(A, Bt, C);
}

// ---------------------------------------------------------------------------
// V (B,L,H,Dh) -> Vt (B,H,Dh,L)
// ---------------------------------------------------------------------------
__global__ __launch_bounds__(256) void transpose_v_k(const u16* __restrict__ V,
                                                     u16* __restrict__ Vt) {
  __shared__ __align__(16) u16 tile[64][65];
  const int z = blockIdx.z;
  const int b = z >> 4, h = z & 15;
  const int l0 = blockIdx.y * 64, d0 = blockIdx.x * 64;
  const int tc = threadIdx.x & 63, tr4 = threadIdx.x >> 6;
#pragma unroll
  for (int p = 0; p < 16; p++) {
    int l = tr4 + p * 4;
    tile[l][tc] = V[(size_t)((b * Lc + l0 + l) * Hc + h) * DhC + d0 + tc];
  }
  __syncthreads();
#pragma unroll
  for (int p = 0; p < 16; p++) {
    int dd = tr4 + p * 4;
    Vt[((size_t)z * DhC + d0 + dd) * Lc + l0 + tc] = tile[tc][dd];
  }
}

// ---------------------------------------------------------------------------
// RoPE in place on Q and K; Q additionally scaled by 1/sqrt(Dh).
// ---------------------------------------------------------------------------
__global__ __launch_bounds__(256) void rope_qk(u16* __restrict__ Q, u16* __restrict__ K) {
  const int idx = blockIdx.x * 256 + threadIdx.x;
  const int j = idx & 63;
  const int l = (idx >> 10) & 2047;
  const float inv = expf(-0.2050369278f * (float)j);  // theta^(-j/64)
  const float ang = (float)l * inv;
  float s, c;
  sincosf(ang, &s, &c);
  const size_t off = (size_t)idx * 2;
  const float q0 = b2f(Q[off]), q1 = b2f(Q[off + 1]);
  const float k0 = b2f(K[off]), k1 = b2f(K[off + 1]);
  const float sc = 0.08838834764f;  // 1/sqrt(128)
  Q[off]     = f2b((q0 * c - q1 * s) * sc);
  Q[off + 1] = f2b((q1 * c + q0 * s) * sc);
  K[off]     = f2b(k0 * c - k1 * s);
  K[off + 1] = f2b(k1 * c + k0 * s);
}

// ---------------------------------------------------------------------------
// Flash attention (causal). r6 vs r4 baseline (206us):
//  - DMA double-buffer K/V: prefetch tile kvt+1 via global_load_lds (zero
//    VGPR cost -- r5's register prefetch spilled: WRITE_SIZE 16->205MB)
//  - ONE barrier per KV tile: Ps is wave-private -> mid-loop barrier removed
//  - XOR-swizzled Ks/Vs (DMA-compatible) kills 16-way ds_read conflicts
//  - heavy-first qt order kept (LPT)
// LDS: 2*16K (Ks) + 2*16K (Vs) + 9K (Ps) = 73KB -> 2 blocks/CU.
// ---------------------------------------------------------------------------
#define NEGBIG (-3.0e30f)
__global__ __launch_bounds__(256) void flash_attn(const u16* __restrict__ Q,
                                                  const u16* __restrict__ Kg,
                                                  const u16* __restrict__ Vt,
                                                  u16* __restrict__ O) {
  __shared__ __align__(16) u16 Ks[2][64 * 128];
  __shared__ __align__(16) u16 Vs[2][128 * 64];
  __shared__ __align__(16) u16 Ps[4][16][72];
  const int tid = threadIdx.x;
  const int lane = tid & 63, w = tid >> 6;
  const int quad = lane >> 4, l15 = lane & 15;
  const int qt = (int)gridDim.x - 1 - (int)blockIdx.x;  // heavy first
  const int bh = blockIdx.y;
  const int b = bh >> 4, h = bh & 15;
  const int q0 = qt * 64;
  const int qrow = q0 + w * 16 + l15;

  // staging maps (wave-uniform LDS bases; per-lane global chunk choice)
  const int krl = lane >> 4, ksl = lane & 15;  // K: 4 rows x 16 chunks / wave
  const int vrl = lane >> 3, vsl = lane & 7;   // V: 8 rows x 8 chunks / wave

  bf16x8 aq[4];
  const u16* qptr = Q + ((size_t)(b * Lc + qrow) * Hc + h) * DhC + quad * 8;
#pragma unroll
  for (int ks = 0; ks < 4; ks++) aq[ks] = *(const bf16x8*)(qptr + ks * 32);

  // prologue: DMA tile 0 into buffer 0
  {
#pragma unroll
    for (int p = 0; p < 4; p++) {
      const int r = p * 16 + w * 4 + krl;
      const int c = ksl ^ (r & 15);
      gll16(Kg + ((size_t)(b * Lc + r) * Hc + h) * DhC + c * 8,
            &Ks[0][(p * 256 + w * 64) * 8]);
    }
#pragma unroll
    for (int p = 0; p < 4; p++) {
      const int r = p * 32 + w * 8 + vrl;
      const int c = vsl ^ (r & 7);
      gll16(Vt + ((size_t)bh * DhC + r) * Lc + c * 8,
            &Vs[0][(p * 256 + w * 64) * 8]);
    }
  }

  const f32x4 fz = {0.f, 0.f, 0.f, 0.f};
  f32x4 o[8];
#pragma unroll
  for (int f = 0; f < 8; f++) o[f] = fz;
  float mrow[4], lrow[4];
#pragma unroll
  for (int r = 0; r < 4; r++) { mrow[r] = NEGBIG; lrow[r] = 0.f; }

  __syncthreads();  // tile 0 DMA complete

  for (int kvt = 0; kvt <= qt; kvt++) {
    const int cur = kvt & 1;
    const u16* Ksc = Ks[cur];
    const u16* Vsc = Vs[cur];

    // prefetch next tile into other buffer (in flight during compute)
    if (kvt < qt) {
      const int nv0 = (kvt + 1) * 64;
      const int nxt = cur ^ 1;
#pragma unroll
      for (int p = 0; p < 4; p++) {
        const int r = p * 16 + w * 4 + krl;
        const int c = ksl ^ (r & 15);
        gll16(Kg + ((size_t)(b * Lc + nv0 + r) * Hc + h) * DhC + c * 8,
              &Ks[nxt][(p * 256 + w * 64) * 8]);
      }
#pragma unroll
      for (int p = 0; p < 4; p++) {
        const int r = p * 32 + w * 8 + vrl;
        const int c = vsl ^ (r & 7);
        gll16(Vt + ((size_t)bh * DhC + r) * Lc + nv0 + c * 8,
              &Vs[nxt][(p * 256 + w * 64) * 8]);
      }
    }

    // S = Q @ K^T (swizzled reads: chunk (ks*4+quad) ^ row&15, row&15 = l15)
    f32x4 s[4];
#pragma unroll
    for (int ct = 0; ct < 4; ct++) s[ct] = fz;
#pragma unroll
    for (int ks = 0; ks < 4; ks++) {
#pragma unroll
      for (int ct = 0; ct < 4; ct++) {
        bf16x8 bk = *(const bf16x8*)(
            &Ksc[(ct * 16 + l15) * 128 + (((ks << 2) + quad) ^ l15) * 8]);
        s[ct] = __builtin_amdgcn_mfma_f32_16x16x32_bf16(aq[ks], bk, s[ct], 0, 0, 0);
      }
    }

    if (kvt == qt) {
      const int kv0 = kvt * 64;
#pragma unroll
      for (int ct = 0; ct < 4; ct++) {
        int kvc = kv0 + ct * 16 + l15;
#pragma unroll
        for (int r = 0; r < 4; r++) {
          int qr = q0 + w * 16 + quad * 4 + r;
          if (kvc > qr) s[ct][r] = NEGBIG;
        }
      }
    }

    // online softmax (rows live across 16 lanes of a quad)
    float mnew[4], alpha[4];
#pragma unroll
    for (int r = 0; r < 4; r++) {
      float mx = fmaxf(fmaxf(s[0][r], s[1][r]), fmaxf(s[2][r], s[3][r]));
#pragma unroll
      for (int off = 1; off < 16; off <<= 1) mx = fmaxf(mx, __shfl_xor(mx, off, 64));
      mnew[r] = fmaxf(mrow[r], mx);
      alpha[r] = __expf(mrow[r] - mnew[r]);
      mrow[r] = mnew[r];
    }
    float psum[4] = {0.f, 0.f, 0.f, 0.f};
#pragma unroll
    for (int ct = 0; ct < 4; ct++) {
#pragma unroll
      for (int r = 0; r < 4; r++) {
        float p = __expf(s[ct][r] - mnew[r]);
        s[ct][r] = p;
        psum[r] += p;
      }
    }
#pragma unroll
    for (int r = 0; r < 4; r++) {
#pragma unroll
      for (int off = 1; off < 16; off <<= 1) psum[r] += __shfl_xor(psum[r], off, 64);
      lrow[r] = lrow[r] * alpha[r] + psum[r];
    }
#pragma unroll
    for (int f = 0; f < 8; f++)
#pragma unroll
      for (int r = 0; r < 4; r++) o[f][r] *= alpha[r];

    // P: C-layout -> LDS -> A-layout. Ps[w] is wave-private: NO barrier
    // needed (in-wave lgkmcnt ordering suffices).
#pragma unroll
    for (int ct = 0; ct < 4; ct++)
#pragma unroll
      for (int r = 0; r < 4; r++)
        Ps[w][quad * 4 + r][ct * 16 + l15] = f2b(s[ct][r]);

    // O += P @ V (swizzled Vs reads: chunk (ks*4+quad) ^ (row&7))
#pragma unroll
    for (int ks = 0; ks < 2; ks++) {
      bf16x8 ap = *(const bf16x8*)(&Ps[w][l15][ks * 32 + quad * 8]);
#pragma unroll
      for (int f = 0; f < 8; f++) {
        bf16x8 bv = *(const bf16x8*)(
            &Vsc[(f * 16 + l15) * 64 + ((((ks << 2) + quad)) ^ (l15 & 7)) * 8]);
        o[f] = __builtin_amdgcn_mfma_f32_16x16x32_bf16(ap, bv, o[f], 0, 0, 0);
      }
    }

    // single barrier per tile: all waves done with buf(cur); prefetch DMA
    // (issued at loop top) is drained by the barrier's vmcnt(0) -- it had
    // the whole compute phase to land.
    __syncthreads();
  }

#pragma unroll
  for (int f = 0; f < 8; f++) {
    int d = f * 16 + l15;
#pragma unroll
    for (int r = 0; r < 4; r++) {
      int qr = q0 + w * 16 + quad * 4 + r;
      O[((size_t)(b * Lc + qr) * Hc + h) * DhC + d] = f2b(o[f][r] / lrow[r]);
    }
  }
}

// ---------------------------------------------------------------------------
// ws layout (72 MiB + 256 B peak), serial weight-slot reuse:
//   [0,256) flag | WT 8MiB | xc 16MiB | Qb 16MiB | Kb 16MiB | Vb 16MiB
//   Vtb aliases xc (dead after V-gemm); Ob aliases Vb (dead after v-transpose)
// ---------------------------------------------------------------------------
extern "C" void kernel_launch(void* const* d_in, const int* in_sizes, int n_in,
                              void* d_out, int out_size, void* d_ws, size_t ws_size,
                              hipStream_t stream) {
  const void* x  = d_in[0];
  const void* Wq = d_in[1];
  const void* Wk = d_in[2];
  const void* Wv = d_in[3];
  const void* Wo = d_in[4];
  float* out = (float*)d_out;   // reference output dtype: float32 (verified r4)

  char* w = (char*)d_ws;
  const size_t WSZ = (size_t)2048 * 2048;
  const size_t XSZ = (size_t)Bb * Lc * Dc;
  int* flag = (int*)w;
  u16* WT  = (u16*)(w + 256);
  u16* xc  = WT + WSZ;
  u16* Qb  = xc + XSZ;
  u16* Kb  = Qb + XSZ;
  u16* Vb  = Kb + XSZ;
  u16* Vtb = xc;
  u16* Ob  = Vb;

  sniff_dtype<<<1, 256, 0, stream>>>((const u16*)x, flag);
  conv_x<<<(int)(XSZ / 1024), 256, 0, stream>>>(x, xc, flag);

  dim3 tgrid(32, 32);
  dim3 ggrid(32, 16);

  transpose2d_conv<<<tgrid, 256, 0, stream>>>(Wq, WT, flag);
  gemm_bt<<<ggrid, 256, 0, stream>>>(xc, WT, Qb);
  transpose2d_conv<<<tgrid, 256, 0, stream>>>(Wk, WT, flag);
  gemm_bt<<<ggrid, 256, 0, stream>>>(xc, WT, Kb);
  transpose2d_conv<<<tgrid, 256, 0, stream>>>(Wv, WT, flag);
  gemm_bt<<<ggrid, 256, 0, stream>>>(xc, WT, Vb);

  rope_qk<<<(Bb * Lc * Hc * 64) / 256, 256, 0, stream>>>(Qb, Kb);

  dim3 vgrid(2, 32, 32);
  transpose_v_k<<<vgrid, 256, 0, stream>>>(Vb, Vtb);

  dim3 fgrid(32, 32);
  flash_attn<<<fgrid, 256, 0, stream>>>(Qb, Kb, Vtb, Ob);

  transpose2d_conv<<<tgrid, 256, 0, stream>>>(Wo, WT, flag);
  gemm_bt_f32<<<ggrid, 256, 0, stream>>>(Ob, WT, out);
}